// Round 9
// baseline (34.191 us; speedup 1.0000x reference)
//
#include <hip/hip_runtime.h>

// x [4096, 3072] fp32.
//   out = ( sum_d (colsum_d)^2 - sum x^4 ) / D,   colsum_d = sum_i x[i,d]^2
// Single fused kernel (r6 k1 geometry: 1536 blocks, NT loads, LDS combine)
// + 12.3 KiB memset node.
// Column partials: relaxed AGENT-scope float atomicAdd into cells[3072]
// (coherent-point ops, no fences, no L2 flush - the r4 mistake avoided).
// Completion ordering: wave0 `s_waitcnt vmcnt(0)` then relaxed counter bump;
// last-arriving block reads cells/q_part with relaxed agent atomic loads and
// does the fixed-order final combine.

typedef float f4 __attribute__((ext_vector_type(4)));

#define NROWS 4096
#define NCOLS 3072
#define NC4     768               // float4 columns
#define GBX     24                // 32 f4-cols per block-x
#define NCHUNK  64                // 64-row chunks
#define NBLK1   (GBX * NCHUNK)    // 1536
#define TPB     256
#define DINV (1.0 / (double)NCOLS)

// ws layout (bytes):
#define WS_CELLS_OFF  0                    // float cells[3072] (memset each call)
#define WS_CNT_OFF    (NCOLS * 4)          // uint counter     (memset each call)
#define WS_ZERO_BYTES (NCOLS * 4 + 4)
#define WS_Q_OFF      (NCOLS * 4 + 128)    // float q_part[1536] (overwritten, no memset)

__global__ __launch_bounds__(TPB) void fused_orthreg(
        const float* __restrict__ x,
        float* __restrict__ cells,
        float* __restrict__ q_part,
        unsigned int* __restrict__ counter,
        float* __restrict__ out) {
    const int t    = threadIdx.x;
    const int tc   = t & 31;                   // f4-col within block
    const int rsub = t >> 5;                   // row-subgroup 0..7
    const int c4   = blockIdx.x * 32 + tc;     // 0..767
    const int r0   = blockIdx.y * 64 + rsub * 8;
    const int bid  = blockIdx.y * GBX + blockIdx.x;
    const f4* __restrict__ xv = (const f4*)x;

    // ---- phase 1: stream (identical to r6 k1) ----
    f4 s = (f4)(0.f);
    float q = 0.f;
    #pragma unroll
    for (int i = 0; i < 8; ++i) {
        f4 v = __builtin_nontemporal_load(&xv[(size_t)(r0 + i) * NC4 + c4]);
        f4 sq = v * v;
        s += sq;
        q = fmaf(sq.x, sq.x, q); q = fmaf(sq.y, sq.y, q);
        q = fmaf(sq.z, sq.z, q); q = fmaf(sq.w, sq.w, q);
    }

    __shared__ f4    part[7][32];
    __shared__ float qs[4];
    __shared__ int   lastflag;
    if (rsub) part[rsub - 1][tc] = s;
    #pragma unroll
    for (int off = 32; off; off >>= 1) q += __shfl_down(q, off);
    if ((t & 63) == 0) qs[t >> 6] = q;
    __syncthreads();

    // ---- phase 2: wave 0 publishes partials (all vmem from wave 0) ----
    if (rsub == 0) {                           // lanes 0..31 of wave 0
        f4 p = ((part[0][tc] + part[1][tc]) + (part[2][tc] + part[3][tc]))
             + ((part[4][tc] + part[5][tc]) + (part[6][tc] + s));
        __hip_atomic_fetch_add(&cells[c4 * 4 + 0], p.x, __ATOMIC_RELAXED, __HIP_MEMORY_SCOPE_AGENT);
        __hip_atomic_fetch_add(&cells[c4 * 4 + 1], p.y, __ATOMIC_RELAXED, __HIP_MEMORY_SCOPE_AGENT);
        __hip_atomic_fetch_add(&cells[c4 * 4 + 2], p.z, __ATOMIC_RELAXED, __HIP_MEMORY_SCOPE_AGENT);
        __hip_atomic_fetch_add(&cells[c4 * 4 + 3], p.w, __ATOMIC_RELAXED, __HIP_MEMORY_SCOPE_AGENT);
        if (t == 0) {
            float qq = (qs[0] + qs[1]) + (qs[2] + qs[3]);
            __hip_atomic_store(&q_part[bid], qq, __ATOMIC_RELAXED, __HIP_MEMORY_SCOPE_AGENT);
            // wave-0's atomics/stores complete at the coherent point, then bump:
            asm volatile("s_waitcnt vmcnt(0)" ::: "memory");
            unsigned int old = __hip_atomic_fetch_add(counter, 1u, __ATOMIC_RELAXED,
                                                      __HIP_MEMORY_SCOPE_AGENT);
            lastflag = (old == NBLK1 - 1);
        }
    }
    __syncthreads();
    if (!lastflag) return;

    // ---- phase 3: last block only - fixed-order final combine ----
    double acc = 0.0;
    #pragma unroll
    for (int i = 0; i < NCOLS / TPB; ++i) {    // 12 cells per thread
        float cv = __hip_atomic_load(&cells[t + i * TPB], __ATOMIC_RELAXED,
                                     __HIP_MEMORY_SCOPE_AGENT);
        double cd = (double)cv;
        acc += cd * cd;
    }
    double qa = 0.0;
    #pragma unroll
    for (int i = 0; i < NBLK1 / TPB; ++i) {    // 6 q-partials per thread
        qa += (double)__hip_atomic_load(&q_part[t + i * TPB], __ATOMIC_RELAXED,
                                        __HIP_MEMORY_SCOPE_AGENT);
    }
    acc -= qa;
    #pragma unroll
    for (int off = 32; off; off >>= 1) acc += __shfl_down(acc, off);
    __shared__ double dd[4];
    if ((t & 63) == 0) dd[t >> 6] = acc;
    __syncthreads();
    if (t == 0) out[0] = (float)(((dd[0] + dd[1]) + (dd[2] + dd[3])) * DINV);
}

extern "C" void kernel_launch(void* const* d_in, const int* in_sizes, int n_in,
                              void* d_out, int out_size, void* d_ws, size_t ws_size,
                              hipStream_t stream) {
    const float* x = (const float*)d_in[0];
    float* out = (float*)d_out;
    char* ws = (char*)d_ws;
    float* cells  = (float*)(ws + WS_CELLS_OFF);
    float* q_part = (float*)(ws + WS_Q_OFF);
    unsigned int* counter = (unsigned int*)(ws + WS_CNT_OFF);

    (void)hipMemsetAsync(ws, 0, WS_ZERO_BYTES, stream);
    fused_orthreg<<<dim3(GBX, NCHUNK), TPB, 0, stream>>>(x, cells, q_part, counter, out);
}

// Round 11
// 17.558 us; speedup vs baseline: 1.9473x; 1.9473x over previous
//
#include <hip/hip_runtime.h>

// x [4096, 3072] fp32.
//   out = ( sum_d (colsum_d)^2 - sum x^4 ) / D,   colsum_d = sum_i x[i,d]^2
// r11 = r6 with ONE variable changed: k1 block shape 32cols x 8rsub ->
//   64cols x 4rsub, so each wave64 NT load is ONE contiguous aligned 1KiB
//   burst (r6: two 512B segments). Same 1536 blocks, same 6 waves/SIMD,
//   same 8 NT loads/thread.
// k1 -> col_part[128][3072] (1.5 MiB) + q_part[1536]. No atomics, no fences.
// k2: 13 blocks (12 stripes of 64 f4-cols + 1 quartic); last-arriving block
//   (scoped atomic counter, validated r2/r5/r6/r8) does the fixed-order
//   final combine. Kernel boundary = the only cross-XCD release/acquire.

typedef float f4 __attribute__((ext_vector_type(4)));

#define NROWS 4096
#define NCOLS 3072
#define NC4     768               // float4 columns
#define GBX     12                // 64 f4-cols per block-x
#define NCHUNK  128               // 32-row chunks
#define NBLK1   (GBX * NCHUNK)    // 1536
#define TPB     256
#define DINV (1.0 / (double)NCOLS)

// ws layout (bytes):
#define WS_CS_OFF  0                               // double cs_part[13]
#define WS_COL_OFF 128                             // float col_part[128][3072] = 1.5 MiB
#define WS_Q_OFF   (WS_COL_OFF + NCHUNK * NCOLS * 4)   // float q_part[1536]
#define WS_CNT_OFF (WS_Q_OFF + NBLK1 * 4)              // uint counter

__global__ __launch_bounds__(TPB) void k1_colsq(const float* __restrict__ x,
                                                float* __restrict__ col_part,
                                                float* __restrict__ q_part,
                                                unsigned int* __restrict__ counter) {
    const int t    = threadIdx.x;
    const int tc   = t & 63;                   // f4-col within block (64 wide)
    const int rsub = t >> 6;                   // row-subgroup 0..3
    const int c4   = blockIdx.x * 64 + tc;     // 0..767
    const int r0   = blockIdx.y * 32 + rsub * 8;
    const f4* __restrict__ xv = (const f4*)x;

    if (t == 0 && blockIdx.x == 0 && blockIdx.y == 0) *counter = 0u;  // published at kernel end

    f4 s = (f4)(0.f);
    float q = 0.f;
    #pragma unroll
    for (int i = 0; i < 8; ++i) {
        // wave64 footprint: 64 lanes x 16B = one aligned 1KiB contiguous burst
        f4 v = __builtin_nontemporal_load(&xv[(size_t)(r0 + i) * NC4 + c4]);
        f4 sq = v * v;
        s += sq;
        q = fmaf(sq.x, sq.x, q); q = fmaf(sq.y, sq.y, q);
        q = fmaf(sq.z, sq.z, q); q = fmaf(sq.w, sq.w, q);
    }

    __shared__ f4    part[3][64];
    __shared__ float qs[4];
    if (rsub) part[rsub - 1][tc] = s;
    #pragma unroll
    for (int off = 32; off; off >>= 1) q += __shfl_down(q, off);
    if ((t & 63) == 0) qs[rsub] = q;
    __syncthreads();

    if (rsub == 0) {        // wave 0: combine 4 row-subgroups, one 1KiB store
        f4 p = (s + part[0][tc]) + (part[1][tc] + part[2][tc]);
        ((f4*)col_part)[(size_t)blockIdx.y * NC4 + c4] = p;
    }
    if (t == 0)
        q_part[blockIdx.y * GBX + blockIdx.x] = (qs[0] + qs[1]) + (qs[2] + qs[3]);
}

__global__ __launch_bounds__(TPB) void k2_finish(const float* __restrict__ col_part,
                                                 const float* __restrict__ q_part,
                                                 double* __restrict__ cs_part,
                                                 unsigned int* __restrict__ counter,
                                                 float* __restrict__ out) {
    const int t = threadIdx.x;
    const int b = blockIdx.x;                  // 0..12
    const int tc = t & 63, rsub = t >> 6;
    __shared__ f4 part[3][64];
    __shared__ double dsh[4];
    double partial = 0.0;

    if (b < 12) {
        // reduce 128 chunk-partials for this stripe's 64 f4-cols
        const f4* __restrict__ cp4 = (const f4*)col_part;
        const int c4 = b * 64 + tc;
        f4 s = (f4)(0.f);
        #pragma unroll
        for (int i = 0; i < 32; ++i)
            s += cp4[(size_t)(rsub * 32 + i) * NC4 + c4];
        if (rsub) part[rsub - 1][tc] = s;
        __syncthreads();
        if (rsub == 0) {
            f4 p0 = part[0][tc], p1 = part[1][tc], p2 = part[2][tc];
            double cx = ((double)s.x + (double)p0.x) + ((double)p1.x + (double)p2.x);
            double cy = ((double)s.y + (double)p0.y) + ((double)p1.y + (double)p2.y);
            double cz = ((double)s.z + (double)p0.z) + ((double)p1.z + (double)p2.z);
            double cw = ((double)s.w + (double)p0.w) + ((double)p1.w + (double)p2.w);
            partial = (cx * cx + cy * cy) + (cz * cz + cw * cw);
            #pragma unroll
            for (int off = 32; off; off >>= 1) partial += __shfl_down(partial, off);
        }
    } else {
        // quartic partials: 1536 entries, 6 per thread
        double qd = 0.0;
        #pragma unroll
        for (int i = 0; i < 6; ++i) qd += (double)q_part[t + i * TPB];
        #pragma unroll
        for (int off = 32; off; off >>= 1) qd += __shfl_down(qd, off);
        if ((t & 63) == 0) dsh[rsub] = qd;
        __syncthreads();
        if (t == 0) partial = (dsh[0] + dsh[1]) + (dsh[2] + dsh[3]);
    }

    if (t == 0) {
        __hip_atomic_store(&cs_part[b], partial, __ATOMIC_RELEASE, __HIP_MEMORY_SCOPE_AGENT);
        unsigned int old = __hip_atomic_fetch_add(counter, 1u, __ATOMIC_ACQ_REL,
                                                  __HIP_MEMORY_SCOPE_AGENT);
        if (old == 12u) {                      // last block: fixed-order combine
            double acc = 0.0;
            #pragma unroll
            for (int i = 0; i < 12; ++i)
                acc += __hip_atomic_load(&cs_part[i], __ATOMIC_ACQUIRE,
                                         __HIP_MEMORY_SCOPE_AGENT);
            acc -= __hip_atomic_load(&cs_part[12], __ATOMIC_ACQUIRE,
                                     __HIP_MEMORY_SCOPE_AGENT);
            out[0] = (float)(acc * DINV);
        }
    }
}

extern "C" void kernel_launch(void* const* d_in, const int* in_sizes, int n_in,
                              void* d_out, int out_size, void* d_ws, size_t ws_size,
                              hipStream_t stream) {
    const float* x = (const float*)d_in[0];
    float* out = (float*)d_out;
    char* ws = (char*)d_ws;
    double* cs_part  = (double*)(ws + WS_CS_OFF);
    float*  col_part = (float*)(ws + WS_COL_OFF);
    float*  q_part   = (float*)(ws + WS_Q_OFF);
    unsigned int* counter = (unsigned int*)(ws + WS_CNT_OFF);

    k1_colsq<<<dim3(GBX, NCHUNK), TPB, 0, stream>>>(x, col_part, q_part, counter);
    k2_finish<<<13, TPB, 0, stream>>>(col_part, q_part, cs_part, counter, out);
}

// Round 12
// 17.199 us; speedup vs baseline: 1.9880x; 1.0209x over previous
//
#include <hip/hip_runtime.h>

// x [4096, 3072] fp32.
//   out = ( sum_d (colsum_d)^2 - sum x^4 ) / D,   colsum_d = sum_i x[i,d]^2
// r12 = r6 with ONE variable changed: streaming loads are inline-asm
//   global_load_dwordx4 ... sc0 sc1 nt  (system-coherent: bypass L2
//   allocation; nt: no retention) instead of __builtin_nontemporal_load
//   (nt only). 8 loads issued back-to-back -> one s_waitcnt vmcnt(0) ->
//   sched_barrier(0) (rule 18) -> math. Named v0..v7 (rule 20).
// k1: 1536 blocks (24 waves/CU), 32 f4-cols x 8 row-subgroups, LDS combine
//     -> col_part[64][3072] (768 KiB) + q_part[1536].
// k2: 13 blocks; last-arriving block (scoped atomic counter, validated
//     r2/r5/r6/r8/r11) does the fixed-order final combine.
// Kernel boundary = the only cross-XCD release/acquire.

typedef float f4 __attribute__((ext_vector_type(4)));

#define NROWS 4096
#define NCOLS 3072
#define NC4     768               // float4 columns
#define GBX     24                // 32 f4-cols per block-x
#define NCHUNK  64                // 64-row chunks
#define NBLK1   (GBX * NCHUNK)    // 1536
#define TPB     256
#define DINV (1.0 / (double)NCOLS)

// ws layout (bytes):
#define WS_CS_OFF  0                               // double cs_part[13]
#define WS_COL_OFF 128                             // float col_part[64][3072] = 768 KiB
#define WS_Q_OFF   (WS_COL_OFF + NCHUNK * NCOLS * 4)   // float q_part[1536]
#define WS_CNT_OFF (WS_Q_OFF + NBLK1 * 4)              // uint counter

__global__ __launch_bounds__(TPB) void k1_colsq(const float* __restrict__ x,
                                                float* __restrict__ col_part,
                                                float* __restrict__ q_part,
                                                unsigned int* __restrict__ counter) {
    const int t    = threadIdx.x;
    const int tc   = t & 31;                   // f4-col within block
    const int rsub = t >> 5;                   // row-subgroup 0..7
    const int c4   = blockIdx.x * 32 + tc;     // 0..767
    const int r0   = blockIdx.y * 64 + rsub * 8;
    const f4* __restrict__ xv = (const f4*)x;

    if (t == 0 && blockIdx.x == 0 && blockIdx.y == 0) *counter = 0u;  // published at kernel end

    // ---- 8 L2-bypassing loads in flight, then one wait ----
    f4 v0, v1, v2, v3, v4, v5, v6, v7;
    {
        const f4* p = xv + (size_t)r0 * NC4 + c4;
        asm volatile("global_load_dwordx4 %0, %1, off sc0 sc1 nt" : "=v"(v0) : "v"(p + 0 * NC4));
        asm volatile("global_load_dwordx4 %0, %1, off sc0 sc1 nt" : "=v"(v1) : "v"(p + 1 * NC4));
        asm volatile("global_load_dwordx4 %0, %1, off sc0 sc1 nt" : "=v"(v2) : "v"(p + 2 * NC4));
        asm volatile("global_load_dwordx4 %0, %1, off sc0 sc1 nt" : "=v"(v3) : "v"(p + 3 * NC4));
        asm volatile("global_load_dwordx4 %0, %1, off sc0 sc1 nt" : "=v"(v4) : "v"(p + 4 * NC4));
        asm volatile("global_load_dwordx4 %0, %1, off sc0 sc1 nt" : "=v"(v5) : "v"(p + 5 * NC4));
        asm volatile("global_load_dwordx4 %0, %1, off sc0 sc1 nt" : "=v"(v6) : "v"(p + 6 * NC4));
        asm volatile("global_load_dwordx4 %0, %1, off sc0 sc1 nt" : "=v"(v7) : "v"(p + 7 * NC4));
        asm volatile("s_waitcnt vmcnt(0)" ::: "memory");
        __builtin_amdgcn_sched_barrier(0);     // rule 18: keep consumers below the wait
    }

    f4 s = (f4)(0.f);
    float q = 0.f;
#define ACC(v) { f4 sq_ = (v) * (v); s += sq_;                      \
                 q = fmaf(sq_.x, sq_.x, q); q = fmaf(sq_.y, sq_.y, q); \
                 q = fmaf(sq_.z, sq_.z, q); q = fmaf(sq_.w, sq_.w, q); }
    ACC(v0) ACC(v1) ACC(v2) ACC(v3) ACC(v4) ACC(v5) ACC(v6) ACC(v7)
#undef ACC

    __shared__ f4    part[7][32];
    __shared__ float qs[4];
    if (rsub) part[rsub - 1][tc] = s;
    #pragma unroll
    for (int off = 32; off; off >>= 1) q += __shfl_down(q, off);
    if ((t & 63) == 0) qs[t >> 6] = q;
    __syncthreads();

    if (rsub == 0) {        // lanes 0..31: combine 8 row-subgroups, one 512B store
        f4 p = ((part[0][tc] + part[1][tc]) + (part[2][tc] + part[3][tc]))
             + ((part[4][tc] + part[5][tc]) + (part[6][tc] + s));
        ((f4*)col_part)[(size_t)blockIdx.y * NC4 + c4] = p;
    }
    if (t == 0)
        q_part[blockIdx.y * GBX + blockIdx.x] = (qs[0] + qs[1]) + (qs[2] + qs[3]);
}

__global__ __launch_bounds__(TPB) void k2_finish(const float* __restrict__ col_part,
                                                 const float* __restrict__ q_part,
                                                 double* __restrict__ cs_part,
                                                 unsigned int* __restrict__ counter,
                                                 float* __restrict__ out) {
    const int t = threadIdx.x;
    const int b = blockIdx.x;                  // 0..12
    const int tc = t & 63, rsub = t >> 6;
    __shared__ f4 part[3][64];
    __shared__ double dsh[4];
    double partial = 0.0;

    if (b < 12) {
        // reduce 64 chunk-partials for this stripe's 64 f4-cols
        const f4* __restrict__ cp4 = (const f4*)col_part;
        const int c4 = b * 64 + tc;
        f4 s = (f4)(0.f);
        #pragma unroll
        for (int i = 0; i < 16; ++i)
            s += cp4[(size_t)(rsub * 16 + i) * NC4 + c4];
        if (rsub) part[rsub - 1][tc] = s;
        __syncthreads();
        if (rsub == 0) {
            f4 p0 = part[0][tc], p1 = part[1][tc], p2 = part[2][tc];
            double cx = ((double)s.x + (double)p0.x) + ((double)p1.x + (double)p2.x);
            double cy = ((double)s.y + (double)p0.y) + ((double)p1.y + (double)p2.y);
            double cz = ((double)s.z + (double)p0.z) + ((double)p1.z + (double)p2.z);
            double cw = ((double)s.w + (double)p0.w) + ((double)p1.w + (double)p2.w);
            partial = (cx * cx + cy * cy) + (cz * cz + cw * cw);
            #pragma unroll
            for (int off = 32; off; off >>= 1) partial += __shfl_down(partial, off);
        }
    } else {
        // quartic partials: 1536 entries, 6 per thread
        double qd = 0.0;
        #pragma unroll
        for (int i = 0; i < 6; ++i) qd += (double)q_part[t + i * TPB];
        #pragma unroll
        for (int off = 32; off; off >>= 1) qd += __shfl_down(qd, off);
        if ((t & 63) == 0) dsh[rsub] = qd;
        __syncthreads();
        if (t == 0) partial = (dsh[0] + dsh[1]) + (dsh[2] + dsh[3]);
    }

    if (t == 0) {
        __hip_atomic_store(&cs_part[b], partial, __ATOMIC_RELEASE, __HIP_MEMORY_SCOPE_AGENT);
        unsigned int old = __hip_atomic_fetch_add(counter, 1u, __ATOMIC_ACQ_REL,
                                                  __HIP_MEMORY_SCOPE_AGENT);
        if (old == 12u) {                      // last block: fixed-order combine
            double acc = 0.0;
            #pragma unroll
            for (int i = 0; i < 12; ++i)
                acc += __hip_atomic_load(&cs_part[i], __ATOMIC_ACQUIRE,
                                         __HIP_MEMORY_SCOPE_AGENT);
            acc -= __hip_atomic_load(&cs_part[12], __ATOMIC_ACQUIRE,
                                     __HIP_MEMORY_SCOPE_AGENT);
            out[0] = (float)(acc * DINV);
        }
    }
}

extern "C" void kernel_launch(void* const* d_in, const int* in_sizes, int n_in,
                              void* d_out, int out_size, void* d_ws, size_t ws_size,
                              hipStream_t stream) {
    const float* x = (const float*)d_in[0];
    float* out = (float*)d_out;
    char* ws = (char*)d_ws;
    double* cs_part  = (double*)(ws + WS_CS_OFF);
    float*  col_part = (float*)(ws + WS_COL_OFF);
    float*  q_part   = (float*)(ws + WS_Q_OFF);
    unsigned int* counter = (unsigned int*)(ws + WS_CNT_OFF);

    k1_colsq<<<dim3(GBX, NCHUNK), TPB, 0, stream>>>(x, col_part, q_part, counter);
    k2_finish<<<13, TPB, 0, stream>>>(col_part, q_part, cs_part, counter, out);
}

// Round 13
// 17.192 us; speedup vs baseline: 1.9888x; 1.0004x over previous
//
#include <hip/hip_runtime.h>

// x [4096, 3072] fp32.
//   out = ( sum_d (colsum_d)^2 - sum x^4 ) / D,   colsum_d = sum_i x[i,d]^2
// r13 = r6 with ONE variable changed: k1's intermediate stores are
//   write-through system-scope (global_store_* sc0 sc1) so NO dirty L2
//   lines remain at the k1->k2 kernel boundary (cheaper end-of-kernel
//   writeback/invalidate); k2 reads the read-once intermediate with
//   nontemporal loads (no allocation). Streaming side = r6 verbatim
//   (NT loads, 1536 blocks, 6 waves/SIMD).
// k2: 13 blocks; last-arriving block (scoped atomic counter, validated
//   r2/r5/r6/r8/r11/r12) does the fixed-order final combine.

typedef float f4 __attribute__((ext_vector_type(4)));

#define NROWS 4096
#define NCOLS 3072
#define NC4     768               // float4 columns
#define GBX     24                // 32 f4-cols per block-x
#define NCHUNK  64                // 64-row chunks
#define NBLK1   (GBX * NCHUNK)    // 1536
#define TPB     256
#define DINV (1.0 / (double)NCOLS)

// ws layout (bytes):
#define WS_CS_OFF  0                               // double cs_part[13]
#define WS_COL_OFF 128                             // float col_part[64][3072] = 768 KiB
#define WS_Q_OFF   (WS_COL_OFF + NCHUNK * NCOLS * 4)   // float q_part[1536]
#define WS_CNT_OFF (WS_Q_OFF + NBLK1 * 4)              // uint counter

__global__ __launch_bounds__(TPB) void k1_colsq(const float* __restrict__ x,
                                                float* __restrict__ col_part,
                                                float* __restrict__ q_part,
                                                unsigned int* __restrict__ counter) {
    const int t    = threadIdx.x;
    const int tc   = t & 31;                   // f4-col within block
    const int rsub = t >> 5;                   // row-subgroup 0..7
    const int c4   = blockIdx.x * 32 + tc;     // 0..767
    const int r0   = blockIdx.y * 64 + rsub * 8;
    const f4* __restrict__ xv = (const f4*)x;

    if (t == 0 && blockIdx.x == 0 && blockIdx.y == 0) *counter = 0u;  // published at kernel end

    f4 s = (f4)(0.f);
    float q = 0.f;
    #pragma unroll
    for (int i = 0; i < 8; ++i) {
        f4 v = __builtin_nontemporal_load(&xv[(size_t)(r0 + i) * NC4 + c4]);
        f4 sq = v * v;
        s += sq;
        q = fmaf(sq.x, sq.x, q); q = fmaf(sq.y, sq.y, q);
        q = fmaf(sq.z, sq.z, q); q = fmaf(sq.w, sq.w, q);
    }

    __shared__ f4    part[7][32];
    __shared__ float qs[4];
    if (rsub) part[rsub - 1][tc] = s;
    #pragma unroll
    for (int off = 32; off; off >>= 1) q += __shfl_down(q, off);
    if ((t & 63) == 0) qs[t >> 6] = q;
    __syncthreads();

    if (rsub == 0) {        // lanes 0..31: combine 8 row-subgroups
        f4 p = ((part[0][tc] + part[1][tc]) + (part[2][tc] + part[3][tc]))
             + ((part[4][tc] + part[5][tc]) + (part[6][tc] + s));
        // write-through system-scope: leaves no dirty L2 line for the boundary
        f4* dst = ((f4*)col_part) + (size_t)blockIdx.y * NC4 + c4;
        asm volatile("global_store_dwordx4 %0, %1, off sc0 sc1"
                     :: "v"(dst), "v"(p) : "memory");
    }
    if (t == 0) {
        float qq = (qs[0] + qs[1]) + (qs[2] + qs[3]);
        float* qdst = &q_part[blockIdx.y * GBX + blockIdx.x];
        asm volatile("global_store_dword %0, %1, off sc0 sc1"
                     :: "v"(qdst), "v"(qq) : "memory");
    }
    // asm stores are invisible to the compiler's end-of-kernel accounting:
    asm volatile("s_waitcnt vmcnt(0)" ::: "memory");
}

__global__ __launch_bounds__(TPB) void k2_finish(const float* __restrict__ col_part,
                                                 const float* __restrict__ q_part,
                                                 double* __restrict__ cs_part,
                                                 unsigned int* __restrict__ counter,
                                                 float* __restrict__ out) {
    const int t = threadIdx.x;
    const int b = blockIdx.x;                  // 0..12
    const int tc = t & 63, rsub = t >> 6;
    __shared__ f4 part[3][64];
    __shared__ double dsh[4];
    double partial = 0.0;

    if (b < 12) {
        // reduce 64 chunk-partials for this stripe's 64 f4-cols (NT reads)
        const f4* __restrict__ cp4 = (const f4*)col_part;
        const int c4 = b * 64 + tc;
        f4 s = (f4)(0.f);
        #pragma unroll
        for (int i = 0; i < 16; ++i)
            s += __builtin_nontemporal_load(&cp4[(size_t)(rsub * 16 + i) * NC4 + c4]);
        if (rsub) part[rsub - 1][tc] = s;
        __syncthreads();
        if (rsub == 0) {
            f4 p0 = part[0][tc], p1 = part[1][tc], p2 = part[2][tc];
            double cx = ((double)s.x + (double)p0.x) + ((double)p1.x + (double)p2.x);
            double cy = ((double)s.y + (double)p0.y) + ((double)p1.y + (double)p2.y);
            double cz = ((double)s.z + (double)p0.z) + ((double)p1.z + (double)p2.z);
            double cw = ((double)s.w + (double)p0.w) + ((double)p1.w + (double)p2.w);
            partial = (cx * cx + cy * cy) + (cz * cz + cw * cw);
            #pragma unroll
            for (int off = 32; off; off >>= 1) partial += __shfl_down(partial, off);
        }
    } else {
        // quartic partials: 1536 entries, 6 per thread (NT reads)
        double qd = 0.0;
        #pragma unroll
        for (int i = 0; i < 6; ++i)
            qd += (double)__builtin_nontemporal_load(&q_part[t + i * TPB]);
        #pragma unroll
        for (int off = 32; off; off >>= 1) qd += __shfl_down(qd, off);
        if ((t & 63) == 0) dsh[rsub] = qd;
        __syncthreads();
        if (t == 0) partial = (dsh[0] + dsh[1]) + (dsh[2] + dsh[3]);
    }

    if (t == 0) {
        __hip_atomic_store(&cs_part[b], partial, __ATOMIC_RELEASE, __HIP_MEMORY_SCOPE_AGENT);
        unsigned int old = __hip_atomic_fetch_add(counter, 1u, __ATOMIC_ACQ_REL,
                                                  __HIP_MEMORY_SCOPE_AGENT);
        if (old == 12u) {                      // last block: fixed-order combine
            double acc = 0.0;
            #pragma unroll
            for (int i = 0; i < 12; ++i)
                acc += __hip_atomic_load(&cs_part[i], __ATOMIC_ACQUIRE,
                                         __HIP_MEMORY_SCOPE_AGENT);
            acc -= __hip_atomic_load(&cs_part[12], __ATOMIC_ACQUIRE,
                                     __HIP_MEMORY_SCOPE_AGENT);
            out[0] = (float)(acc * DINV);
        }
    }
}

extern "C" void kernel_launch(void* const* d_in, const int* in_sizes, int n_in,
                              void* d_out, int out_size, void* d_ws, size_t ws_size,
                              hipStream_t stream) {
    const float* x = (const float*)d_in[0];
    float* out = (float*)d_out;
    char* ws = (char*)d_ws;
    double* cs_part  = (double*)(ws + WS_CS_OFF);
    float*  col_part = (float*)(ws + WS_COL_OFF);
    float*  q_part   = (float*)(ws + WS_Q_OFF);
    unsigned int* counter = (unsigned int*)(ws + WS_CNT_OFF);

    k1_colsq<<<dim3(GBX, NCHUNK), TPB, 0, stream>>>(x, col_part, q_part, counter);
    k2_finish<<<13, TPB, 0, stream>>>(col_part, q_part, cs_part, counter, out);
}

// Round 14
// 15.764 us; speedup vs baseline: 2.1689x; 1.0906x over previous
//
#include <hip/hip_runtime.h>

// x [4096, 3072] fp32.
//   out = ( sum_d (colsum_d)^2 - sum x^4 ) / D,   colsum_d = sum_i x[i,d]^2
// r14 = r6 k1 verbatim + WIDENED k2: 49 blocks (48 stripes of 16 f4-cols,
//   4 loads/thread = one memory round trip, + 1 quartic block) and the final
//   49-entry combine parallelized across one wave (fixed shuffle tree,
//   deterministic) instead of 12 serial loads at t==0.
// Probe ledger: NT +1.4us; TLP>6blk/CU, contiguity, L2-bypass, boundary-WT
//   all flat; memset-node fusion dead (~10-40us fixed node cost, r9).
// Kernel boundary = the only cross-XCD release/acquire; k1 resets counter.

typedef float f4 __attribute__((ext_vector_type(4)));

#define NROWS 4096
#define NCOLS 3072
#define NC4     768               // float4 columns
#define GBX     24                // 32 f4-cols per block-x
#define NCHUNK  64                // 64-row chunks
#define NBLK1   (GBX * NCHUNK)    // 1536
#define TPB     256
#define NSTRIPE 48                // k2 stripes of 16 f4-cols
#define DINV (1.0 / (double)NCOLS)

// ws layout (bytes):
#define WS_CS_OFF  0                               // double cs_part[49]
#define WS_COL_OFF 512                             // float col_part[64][3072] = 768 KiB
#define WS_Q_OFF   (WS_COL_OFF + NCHUNK * NCOLS * 4)   // float q_part[1536]
#define WS_CNT_OFF (WS_Q_OFF + NBLK1 * 4)              // uint counter

__global__ __launch_bounds__(TPB) void k1_colsq(const float* __restrict__ x,
                                                float* __restrict__ col_part,
                                                float* __restrict__ q_part,
                                                unsigned int* __restrict__ counter) {
    const int t    = threadIdx.x;
    const int tc   = t & 31;                   // f4-col within block
    const int rsub = t >> 5;                   // row-subgroup 0..7
    const int c4   = blockIdx.x * 32 + tc;     // 0..767
    const int r0   = blockIdx.y * 64 + rsub * 8;
    const f4* __restrict__ xv = (const f4*)x;

    if (t == 0 && blockIdx.x == 0 && blockIdx.y == 0) *counter = 0u;  // published at kernel end

    f4 s = (f4)(0.f);
    float q = 0.f;
    #pragma unroll
    for (int i = 0; i < 8; ++i) {
        f4 v = __builtin_nontemporal_load(&xv[(size_t)(r0 + i) * NC4 + c4]);
        f4 sq = v * v;
        s += sq;
        q = fmaf(sq.x, sq.x, q); q = fmaf(sq.y, sq.y, q);
        q = fmaf(sq.z, sq.z, q); q = fmaf(sq.w, sq.w, q);
    }

    __shared__ f4    part[7][32];
    __shared__ float qs[4];
    if (rsub) part[rsub - 1][tc] = s;
    #pragma unroll
    for (int off = 32; off; off >>= 1) q += __shfl_down(q, off);
    if ((t & 63) == 0) qs[t >> 6] = q;
    __syncthreads();

    if (rsub == 0) {        // lanes 0..31: combine 8 row-subgroups, one 512B store
        f4 p = ((part[0][tc] + part[1][tc]) + (part[2][tc] + part[3][tc]))
             + ((part[4][tc] + part[5][tc]) + (part[6][tc] + s));
        ((f4*)col_part)[(size_t)blockIdx.y * NC4 + c4] = p;
    }
    if (t == 0)
        q_part[blockIdx.y * GBX + blockIdx.x] = (qs[0] + qs[1]) + (qs[2] + qs[3]);
}

__global__ __launch_bounds__(TPB) void k2_finish(const float* __restrict__ col_part,
                                                 const float* __restrict__ q_part,
                                                 double* __restrict__ cs_part,
                                                 unsigned int* __restrict__ counter,
                                                 float* __restrict__ out) {
    const int t = threadIdx.x;
    const int b = blockIdx.x;                  // 0..48
    __shared__ f4 acc[16][16];
    __shared__ double dsh[4];
    __shared__ int lastflag;
    double partial = 0.0;

    if (b < NSTRIPE) {
        // stripe = 16 f4-cols; 256 threads = 16 cols x 16 chunk-groups,
        // 4 independent NT loads each = one memory round trip.
        const f4* __restrict__ cp4 = (const f4*)col_part;
        const int tc = t & 15, grp = t >> 4;
        f4 s = (f4)(0.f);
        #pragma unroll
        for (int i = 0; i < 4; ++i)
            s += __builtin_nontemporal_load(
                     &cp4[(size_t)(grp * 4 + i) * NC4 + b * 16 + tc]);
        acc[grp][tc] = s;
        __syncthreads();
        if (t < 16) {                          // lanes 0..15 of wave 0
            f4 tot = (((acc[0][t] + acc[1][t]) + (acc[2][t] + acc[3][t]))
                    + ((acc[4][t] + acc[5][t]) + (acc[6][t] + acc[7][t])))
                   + (((acc[8][t] + acc[9][t]) + (acc[10][t] + acc[11][t]))
                    + ((acc[12][t] + acc[13][t]) + (acc[14][t] + acc[15][t])));
            double pr = ((double)tot.x * (double)tot.x + (double)tot.y * (double)tot.y)
                      + ((double)tot.z * (double)tot.z + (double)tot.w * (double)tot.w);
            #pragma unroll
            for (int off = 8; off; off >>= 1) pr += __shfl_down(pr, off);
            partial = pr;                      // valid at t==0
        }
    } else {
        // quartic partials: 1536 entries, 6 per thread (NT reads)
        double qd = 0.0;
        #pragma unroll
        for (int i = 0; i < 6; ++i)
            qd += (double)__builtin_nontemporal_load(&q_part[t + i * TPB]);
        #pragma unroll
        for (int off = 32; off; off >>= 1) qd += __shfl_down(qd, off);
        if ((t & 63) == 0) dsh[t >> 6] = qd;
        __syncthreads();
        if (t == 0) partial = (dsh[0] + dsh[1]) + (dsh[2] + dsh[3]);
    }

    if (t == 0) {
        __hip_atomic_store(&cs_part[b], partial, __ATOMIC_RELEASE, __HIP_MEMORY_SCOPE_AGENT);
        unsigned int old = __hip_atomic_fetch_add(counter, 1u, __ATOMIC_ACQ_REL,
                                                  __HIP_MEMORY_SCOPE_AGENT);
        lastflag = (old == NSTRIPE);
    }
    __syncthreads();
    if (lastflag && t < 64) {                  // last block: parallel fixed-tree combine
        double v = 0.0;
        if (t < NSTRIPE)
            v = __hip_atomic_load(&cs_part[t], __ATOMIC_ACQUIRE, __HIP_MEMORY_SCOPE_AGENT);
        else if (t == NSTRIPE)
            v = -__hip_atomic_load(&cs_part[NSTRIPE], __ATOMIC_ACQUIRE, __HIP_MEMORY_SCOPE_AGENT);
        #pragma unroll
        for (int off = 32; off; off >>= 1) v += __shfl_down(v, off);
        if (t == 0) out[0] = (float)(v * DINV);
    }
}

extern "C" void kernel_launch(void* const* d_in, const int* in_sizes, int n_in,
                              void* d_out, int out_size, void* d_ws, size_t ws_size,
                              hipStream_t stream) {
    const float* x = (const float*)d_in[0];
    float* out = (float*)d_out;
    char* ws = (char*)d_ws;
    double* cs_part  = (double*)(ws + WS_CS_OFF);
    float*  col_part = (float*)(ws + WS_COL_OFF);
    float*  q_part   = (float*)(ws + WS_Q_OFF);
    unsigned int* counter = (unsigned int*)(ws + WS_CNT_OFF);

    k1_colsq<<<dim3(GBX, NCHUNK), TPB, 0, stream>>>(x, col_part, q_part, counter);
    k2_finish<<<NSTRIPE + 1, TPB, 0, stream>>>(col_part, q_part, cs_part, counter, out);
}